// Round 6
// baseline (194.610 us; speedup 1.0000x reference)
//
#include <hip/hip_runtime.h>
#include <math.h>

// Problem constants (fixed shapes)
#define DIM    4096
#define NH     32
#define NKV    8
#define HD     128
#define BS     16
#define KVLEN  4096
#define LASTPOS 4095
#define QKV_COLS 6144   // 4096 q + 1024 k + 1024 v
#define NKC    64       // k-chunks for split-K projections

typedef float f32x4 __attribute__((ext_vector_type(4)));

__device__ __forceinline__ f32x4 ntload4(const float* p) {
  return __builtin_nontemporal_load((const f32x4*)p);
}

// ws layout (floats):
//   qkv   : [16][6144]             @ 0          (98304)
//   attn  : [16][4096]             @ 98304      (65536)
//   part  : [128][128][4][132]     @ 163840     (8650752)   unit=32 kv rows
//   part2 : [512][4][132]          @ 8814592    (270336)
//   pq    : [64][16][6144]         @ 9084928    (6291456)
//   pw    : [64][16][4096]         @ 15376384   (4194304)   end 19570688 (~78MB)
#define WS_QKV   0
#define WS_ATTN  98304
#define WS_PART  163840
#define WS_PART2 8814592
#define WS_PQ    9084928
#define WS_PW    15376384

// ---------------------------------------------------------------------------
// K1a: qkv partials. block: 256 thr, 2 cols/thread (512 cols); grid (12, 64).
// ---------------------------------------------------------------------------
__global__ __launch_bounds__(256) void qkv_projA(
    const float* __restrict__ x, const float* __restrict__ wq,
    const float* __restrict__ wk, const float* __restrict__ wv,
    float* __restrict__ pq) {
  __shared__ float xs[16 * 64];
  const int tid = threadIdx.x;
  const int col = (blockIdx.x * 256 + tid) * 2;   // block-uniform matrix select
  const int kc = blockIdx.y;
  const int k0 = kc * 64;

  for (int i = tid; i < 1024; i += 256) {
    int b = i >> 6, k = i & 63;
    xs[i] = x[b * DIM + k0 + k];
  }
  __syncthreads();

  const float* w;
  int wstride, wcol;
  if (col < 4096)      { w = wq; wstride = 4096; wcol = col; }
  else if (col < 5120) { w = wk; wstride = 1024; wcol = col - 4096; }
  else                 { w = wv; wstride = 1024; wcol = col - 5120; }
  const float* wp = w + (size_t)k0 * wstride + wcol;

  float acc0[16], acc1[16];
#pragma unroll
  for (int b = 0; b < 16; ++b) { acc0[b] = 0.f; acc1[b] = 0.f; }

#pragma unroll 2
  for (int k = 0; k < 64; k += 4) {
    float2 w0 = *(const float2*)(wp + (size_t)(k + 0) * wstride);
    float2 w1 = *(const float2*)(wp + (size_t)(k + 1) * wstride);
    float2 w2 = *(const float2*)(wp + (size_t)(k + 2) * wstride);
    float2 w3 = *(const float2*)(wp + (size_t)(k + 3) * wstride);
#pragma unroll
    for (int b = 0; b < 16; ++b) {
      float4 xb = *(const float4*)(&xs[b * 64 + k]);
      acc0[b] += xb.x * w0.x + xb.y * w1.x + xb.z * w2.x + xb.w * w3.x;
      acc1[b] += xb.x * w0.y + xb.y * w1.y + xb.z * w2.y + xb.w * w3.y;
    }
  }
#pragma unroll
  for (int b = 0; b < 16; ++b) {
    *(float2*)(&pq[((size_t)kc * 16 + b) * QKV_COLS + col]) = make_float2(acc0[b], acc1[b]);
  }
}

// ---------------------------------------------------------------------------
// K1b: reduce 64 qkv partials + fused RoPE (+ q scale).
// ---------------------------------------------------------------------------
__global__ __launch_bounds__(256) void qkv_projB(
    const float* __restrict__ pq, float* __restrict__ qkv,
    const float* __restrict__ fc, const float* __restrict__ fs) {
  int t = blockIdx.x * 256 + threadIdx.x;       // 0..49151
  int b = t / 3072, pr = t % 3072;
  int col = 2 * pr;
  float e = 0.f, o = 0.f;
#pragma unroll 8
  for (int kc = 0; kc < NKC; ++kc) {
    float2 v = *(const float2*)(&pq[((size_t)kc * 16 + b) * QKV_COLS + col]);
    e += v.x; o += v.y;
  }
  float re = e, im = o;
  if (col < 5120) {  // q or k: rope
    int i = (col & 127) >> 1;
    float c = fc[i], s = fs[i];
    float scale = (col < 4096) ? 0.08838834764831845f : 1.0f;
    re = (e * c - o * s) * scale;
    im = (e * s + o * c) * scale;
  }
  *(float2*)(&qkv[b * QKV_COLS + col]) = make_float2(re, im);
}

// ---------------------------------------------------------------------------
// K3: attention partials — barrier-free, LDS-free. 256 thr = 4 independent
// waves. Block = (b, g, 128-row chunk); wave owns 32 rows (one "unit").
// Scores: 16-lane group per K row (4 rows in parallel, 8 iters), lane holds
//   8 d-elems, shfl_xor(1,2,4,8) reduce; lane keeps sv8[it] = score of
//   (row 4*it + (lane>>4), head lane&3).
// Softmax: per-wave, per-head max/sum via full-unroll regs + shfl_xor(16,32).
// PV: half-wave owns a row (float4 per lane over d), probabilities pulled
//   from score-owner lanes via __shfl; shfl_xor(32) combine; direct store.
// ---------------------------------------------------------------------------
__global__ __launch_bounds__(256, 4) void attn_partial(
    const float* __restrict__ cache_k, const float* __restrict__ cache_v,
    const float* __restrict__ qkv, float* __restrict__ part) {
  const int tid = threadIdx.x;
  const int w = tid >> 6, lane = tid & 63;
  const int p = lane >> 4, ql = lane & 15;
  const int chunk = blockIdx.x & 31;            // 128-row chunk
  const int bg = blockIdx.x >> 5;
  const int b = bg >> 3, g = bg & 7;
  const int unit = chunk * 4 + w;               // 0..127
  const int t0w = chunk * 128 + w * 32;         // first kv row of this wave

  // Q fragments straight from global (L2-hot): head h, d = [ql*8, ql*8+8)
  const float* qbase = qkv + b * QKV_COLS + g * 512;
  f32x4 qA[4], qB[4];
#pragma unroll
  for (int h = 0; h < 4; ++h) {
    qA[h] = *(const f32x4*)(qbase + h * 128 + ql * 8);
    qB[h] = *(const f32x4*)(qbase + h * 128 + ql * 8 + 4);
  }

  const float* kbase = cache_k + ((size_t)b * 4096 * 8 + g) * 128;
  const float* xk    = qkv + b * QKV_COLS + 4096 + g * 128;

  // ---- scores: sv8[it] = S[row 4it+p][head ql&3] ----
  float sv8[8];
#pragma unroll
  for (int it = 0; it < 8; ++it) {
    int t = t0w + it * 4 + p;
    const float* krow = (t == LASTPOS) ? xk : (kbase + (size_t)t * 1024);
    f32x4 k0 = ntload4(krow + ql * 8);
    f32x4 k1 = ntload4(krow + ql * 8 + 4);
    float s[4];
#pragma unroll
    for (int h = 0; h < 4; ++h) {
      s[h] = k0[0]*qA[h][0] + k0[1]*qA[h][1] + k0[2]*qA[h][2] + k0[3]*qA[h][3]
           + k1[0]*qB[h][0] + k1[1]*qB[h][1] + k1[2]*qB[h][2] + k1[3]*qB[h][3];
    }
#pragma unroll
    for (int off = 1; off < 16; off <<= 1) {
#pragma unroll
      for (int h = 0; h < 4; ++h) s[h] += __shfl_xor(s[h], off);
    }
    int hsel = ql & 3;
    float v = s[0];
    if (hsel == 1) v = s[1];
    if (hsel == 2) v = s[2];
    if (hsel == 3) v = s[3];
    sv8[it] = v;
  }

  // ---- per-wave softmax for head (ql&3) over 32 rows ----
  float m = -1e30f;
#pragma unroll
  for (int it = 0; it < 8; ++it) m = fmaxf(m, sv8[it]);
  m = fmaxf(m, __shfl_xor(m, 16));
  m = fmaxf(m, __shfl_xor(m, 32));
  float l = 0.f;
#pragma unroll
  for (int it = 0; it < 8; ++it) { sv8[it] = __expf(sv8[it] - m); l += sv8[it]; }
  l += __shfl_xor(l, 16);
  l += __shfl_xor(l, 32);
  if (lane < 4) {
    size_t pi = ((size_t)(bg * 128 + unit) * 4 + lane) * 132;
    part[pi + 128] = m;
    part[pi + 129] = l;
  }

  // ---- PV: half-wave owns a row; lane covers d = dq*4..dq*4+3 ----
  const float* vbase = cache_v + ((size_t)b * 4096 * 8 + g) * 128;
  const float* xv    = qkv + b * QKV_COLS + 5120 + g * 128;
  const int h2 = lane >> 5;
  const int dq = lane & 31;
  f32x4 acc[4];
#pragma unroll
  for (int h = 0; h < 4; ++h) acc[h] = (f32x4)(0.f);

#pragma unroll
  for (int jj = 0; jj < 16; ++jj) {
    int lr = 2 * jj + h2;                     // local row 0..31
    int t = t0w + lr;
    const float* vrow = (t == LASTPOS) ? xv : (vbase + (size_t)t * 1024);
    f32x4 vv = ntload4(vrow + dq * 4);
    float sreg = sv8[jj >> 1];                // compile-time index
    int srcb = (lr & 3) << 4;
    float p0 = __shfl(sreg, srcb + 0);
    float p1 = __shfl(sreg, srcb + 1);
    float p2 = __shfl(sreg, srcb + 2);
    float p3 = __shfl(sreg, srcb + 3);
    acc[0] += p0 * vv;
    acc[1] += p1 * vv;
    acc[2] += p2 * vv;
    acc[3] += p3 * vv;
  }
#pragma unroll
  for (int h = 0; h < 4; ++h) {
    acc[h][0] += __shfl_xor(acc[h][0], 32);
    acc[h][1] += __shfl_xor(acc[h][1], 32);
    acc[h][2] += __shfl_xor(acc[h][2], 32);
    acc[h][3] += __shfl_xor(acc[h][3], 32);
  }
  if (lane < 32) {
#pragma unroll
    for (int h = 0; h < 4; ++h) {
      size_t pi = ((size_t)(bg * 128 + unit) * 4 + h) * 132;
      *(f32x4*)(&part[pi + dq * 4]) = acc[h];
    }
  }
}

// ---------------------------------------------------------------------------
// K4a: merge 32 units -> per-(bg, s) partial. grid 512 blocks, 512 thr.
// ---------------------------------------------------------------------------
__global__ __launch_bounds__(512) void attn_combine1(
    const float* __restrict__ part, float* __restrict__ part2) {
  const int bgs = blockIdx.x;            // 0..511
  const int bg = bgs >> 2, s = bgs & 3;
  const int tid = threadIdx.x;
  __shared__ float ml[32][4][2];
  for (int i = tid; i < 256; i += 512) {
    int u = i >> 3, h = (i >> 1) & 3, q = i & 1;
    ml[u][h][q] = part[((size_t)(bg * 128 + s * 32 + u) * 4 + h) * 132 + 128 + q];
  }
  __syncthreads();
  const int h = tid >> 7, d = tid & 127;
  float M = -1e30f;
#pragma unroll
  for (int u = 0; u < 32; ++u) M = fmaxf(M, ml[u][h][0]);
  float num = 0.f, den = 0.f;
#pragma unroll 4
  for (int u = 0; u < 32; ++u) {
    float wgt = __expf(ml[u][h][0] - M);
    num += wgt * part[((size_t)(bg * 128 + s * 32 + u) * 4 + h) * 132 + d];
    den += wgt * ml[u][h][1];
  }
  size_t po = ((size_t)bgs * 4 + h) * 132;
  part2[po + d] = num;
  if (d == 0) { part2[po + 128] = M; part2[po + 129] = den; }
}

// ---------------------------------------------------------------------------
// K4b: merge the 4 s-partials -> attn_out. 65536 threads.
// ---------------------------------------------------------------------------
__global__ __launch_bounds__(256) void attn_combine2(
    const float* __restrict__ part2, float* __restrict__ attn_out) {
  int t = blockIdx.x * 256 + threadIdx.x;   // 0..65535
  int d = t & 127, h = (t >> 7) & 3, bg = t >> 9;
  int b = bg >> 3, g = bg & 7;
  float ms[4];
  float M = -1e30f;
#pragma unroll
  for (int s = 0; s < 4; ++s) {
    ms[s] = part2[((size_t)(bg * 4 + s) * 4 + h) * 132 + 128];
    M = fmaxf(M, ms[s]);
  }
  float num = 0.f, den = 0.f;
#pragma unroll
  for (int s = 0; s < 4; ++s) {
    const float* pr = part2 + ((size_t)(bg * 4 + s) * 4 + h) * 132;
    float wgt = __expf(ms[s] - M);
    num += wgt * pr[d];
    den += wgt * pr[129];
  }
  attn_out[b * DIM + (g * 4 + h) * 128 + d] = num / den;
}

// ---------------------------------------------------------------------------
// K5a: wo partials. block: 256 thr, 2 cols/thread (512 cols); grid (8, 64).
// ---------------------------------------------------------------------------
__global__ __launch_bounds__(256) void out_projA(
    const float* __restrict__ attn, const float* __restrict__ wo,
    float* __restrict__ pw) {
  __shared__ float xs[16 * 64];
  const int tid = threadIdx.x;
  const int col = (blockIdx.x * 256 + tid) * 2;  // 0..4094
  const int kc = blockIdx.y;
  const int k0 = kc * 64;

  for (int i = tid; i < 1024; i += 256) {
    int b = i >> 6, k = i & 63;
    xs[i] = attn[b * DIM + k0 + k];
  }
  __syncthreads();

  const float* wp = wo + (size_t)k0 * 4096 + col;
  float acc0[16], acc1[16];
#pragma unroll
  for (int b = 0; b < 16; ++b) { acc0[b] = 0.f; acc1[b] = 0.f; }

#pragma unroll 2
  for (int k = 0; k < 64; k += 4) {
    float2 w0 = *(const float2*)(wp + (size_t)(k + 0) * 4096);
    float2 w1 = *(const float2*)(wp + (size_t)(k + 1) * 4096);
    float2 w2 = *(const float2*)(wp + (size_t)(k + 2) * 4096);
    float2 w3 = *(const float2*)(wp + (size_t)(k + 3) * 4096);
#pragma unroll
    for (int b = 0; b < 16; ++b) {
      float4 xb = *(const float4*)(&xs[b * 64 + k]);
      acc0[b] += xb.x * w0.x + xb.y * w1.x + xb.z * w2.x + xb.w * w3.x;
      acc1[b] += xb.x * w0.y + xb.y * w1.y + xb.z * w2.y + xb.w * w3.y;
    }
  }
#pragma unroll
  for (int b = 0; b < 16; ++b) {
    *(float2*)(&pw[((size_t)kc * 16 + b) * DIM + col]) = make_float2(acc0[b], acc1[b]);
  }
}

// ---------------------------------------------------------------------------
// K5b: reduce 64 wo partials -> d_out.
// ---------------------------------------------------------------------------
__global__ __launch_bounds__(256) void out_projB(
    const float* __restrict__ pw, float* __restrict__ out) {
  int t = blockIdx.x * 256 + threadIdx.x;  // 65536
  int b = t >> 12, col = t & 4095;
  float sum = 0.f;
#pragma unroll 8
  for (int kc = 0; kc < NKC; ++kc)
    sum += pw[((size_t)kc * 16 + b) * DIM + col];
  out[b * DIM + col] = sum;
}

// ---------------------------------------------------------------------------
extern "C" void kernel_launch(void* const* d_in, const int* in_sizes, int n_in,
                              void* d_out, int out_size, void* d_ws, size_t ws_size,
                              hipStream_t stream) {
  const float* x  = (const float*)d_in[0];
  const float* wq = (const float*)d_in[1];
  const float* wk = (const float*)d_in[2];
  const float* wv = (const float*)d_in[3];
  const float* wo = (const float*)d_in[4];
  const float* ck = (const float*)d_in[5];
  const float* cv = (const float*)d_in[6];
  const float* fc = (const float*)d_in[7];
  const float* fs = (const float*)d_in[8];

  float* ws_f  = (float*)d_ws;
  float* qkv   = ws_f + WS_QKV;
  float* attn  = ws_f + WS_ATTN;
  float* part  = ws_f + WS_PART;
  float* part2 = ws_f + WS_PART2;
  float* pq    = ws_f + WS_PQ;
  float* pw    = ws_f + WS_PW;
  float* out   = (float*)d_out;

  qkv_projA<<<dim3(12, NKC), 256, 0, stream>>>(x, wq, wk, wv, pq);
  qkv_projB<<<192, 256, 0, stream>>>(pq, qkv, fc, fs);
  attn_partial<<<4096, 256, 0, stream>>>(ck, cv, qkv, part);
  attn_combine1<<<512, 512, 0, stream>>>(part, part2);
  attn_combine2<<<256, 256, 0, stream>>>(part2, attn);
  out_projA<<<dim3(8, NKC), 256, 0, stream>>>(attn, wo, pw);
  out_projB<<<256, 256, 0, stream>>>(pw, out);
}